// Round 1
// baseline (117.664 us; speedup 1.0000x reference)
//
#include <hip/hip_runtime.h>

// Problem constants (fixed by the reference module)
#define B_ 16
#define L_ 2048
#define D_ 128
#define GROUP_ 16
#define NG_ (L_ / GROUP_)   // 128
#define LOG2E_ 1.44269504088896340736f

typedef float v2 __attribute__((ext_vector_type(2)));

// DPP-based butterfly add (full-rate VALU, no LDS round-trip).
template<int CTRL>
__device__ __forceinline__ float dpp_add(float v) {
    int x = __builtin_amdgcn_update_dpp(0, __float_as_int(v), CTRL, 0xF, 0xF, false);
    return v + __int_as_float(x);
}

// Sum across a 32-lane row (lanes 0..31 and 32..63 reduce independently).
// 4 DPP stages within each 16-lane DPP row, then one ds_swizzle (lane^16)
// to cross the 16-lane boundary inside the 32-lane group.
__device__ __forceinline__ float row32_sum(float v) {
    v = dpp_add<0xB1>(v);   // quad_perm(1,0,3,2)  ~ xor 1
    v = dpp_add<0x4E>(v);   // quad_perm(2,3,0,1)  ~ xor 2
    v = dpp_add<0x141>(v);  // row_half_mirror     ~ xor 4
    v = dpp_add<0x140>(v);  // row_mirror          ~ xor 8
    int s = __builtin_amdgcn_ds_swizzle(__float_as_int(v), 0x401F); // xor 16 (bit-mode, 32-lane groups)
    return v + __int_as_float(s);
}

// One block per (b,g) group. 512 threads = 16 rows x 32 lanes, 4 elems/thread.
//
// R10 rationale: the 256-thread/8-elem version declared 64+ VGPRs of live
// state but compiled to VGPR_Count=44 -> the allocator (targeting the
// 8-wave/SIMD 64-VGPR budget) was demoting ~32 regs of per-dim constants
// and re-materializing them every j-step, with __syncthreads draining the
// resulting traffic on the critical path (VALUBusy 60%, Occ 33%).
// Halving per-thread width makes the whole live set (~52 VGPRs: 24 consts
// + 8 state + temps) genuinely fit at 8 waves/SIMD: zero spills, zero
// per-step reloads, full-occupancy two-pass schedule (4 blocks/CU x 2).
// Numerics bitwise identical to the previous kernel.
__global__ __launch_bounds__(512, 8) void ncn_kernel(
    const float* __restrict__ x,       // (B, L, D)
    const int*   __restrict__ gt,      // (B, L) permutation
    const int*   __restrict__ ctxlens, // (B,)
    const float* __restrict__ W,       // (2D,)
    const float* __restrict__ nalpha,  // (2,)
    const float* __restrict__ ngamma,  // (2D,)
    const float* __restrict__ nbeta,   // (2D,)
    float* __restrict__ out)           // (2, B, L, D) concat: yi_out, ya_out
{
    const int blk = blockIdx.x;
    const int b   = blk >> 7;      // / NG_
    const int g   = blk & (NG_ - 1);
    const int tid = threadIdx.x;
    const int row = tid >> 5;      // 0..15 (token within group)
    const int rl  = tid & 31;      // 0..31 (lane within row)
    const int d0  = rl << 2;       // 4 d-elements per thread

    __shared__ float s_xj[2][D_];  // double-buffered broadcast row

    const float a1 = nalpha[0];
    const float a2 = nalpha[1];
    const float ca = -a1 * LOG2E_;        // u = ca*(xi + sim*xj) = -2*a1*log2e*T
    const float S  = -2.0f * a2 * LOG2E_; // za = S*xa, so exp2(za) direct
    const bool  selMin = (S < 0.0f);      // leaky-relu under sign flip

    // Per-thread constants (reused 16x): 6 arrays x 2 v2 = 24 VGPRs.
    v2 Wi[2], Wj[2], G1S[2], B1S[2], G2[2], B2[2];
    {
        float4 w  = *(const float4*)(W + d0);
        float4 wv = *(const float4*)(W + D_ + d0);
        Wi[0] = (v2){w.x,  w.y};  Wi[1] = (v2){w.z,  w.w};
        Wj[0] = (v2){wv.x, wv.y}; Wj[1] = (v2){wv.z, wv.w};

        float4 g1 = *(const float4*)(ngamma + d0);
        float4 g2 = *(const float4*)(ngamma + D_ + d0);
        float4 b1 = *(const float4*)(nbeta + d0);
        float4 b2 = *(const float4*)(nbeta + D_ + d0);
        v2 g1v[2] = {(v2){g1.x, g1.y}, (v2){g1.z, g1.w}};
        v2 g2v[2] = {(v2){g2.x, g2.y}, (v2){g2.z, g2.w}};
        v2 b1v[2] = {(v2){b1.x, b1.y}, (v2){b1.z, b1.w}};
        v2 b2v[2] = {(v2){b2.x, b2.y}, (v2){b2.z, b2.w}};
#pragma unroll
        for (int k = 0; k < 2; ++k) {
            G1S[k] = (S * 2.0f) * g1v[k];        // S*(2*g1)
            B1S[k] = S * (b1v[k] - g1v[k]);      // S*(b1-g1)
            G2[k]  = 2.0f * g2v[k];
            B2[k]  = b2v[k] - g2v[k];
        }
    }

    // Gather this row's token
    const int l   = g * GROUP_ + row;
    const int tok = gt[b * L_ + l];
    const float* xp = x + ((size_t)(b * L_ + tok)) * D_ + d0;

    v2 xi[2], za[2];
    float4 xA = *(const float4*)xp;
    xi[0] = (v2){xA.x, xA.y}; xi[1] = (v2){xA.z, xA.w};
    za[0] = (v2){0.0f, 0.0f}; za[1] = (v2){0.0f, 0.0f};

    // Row 0 publishes its initial xi into buffer 0
    if (row == 0) *(float4*)&s_xj[0][d0] = xA;
    __syncthreads();

#pragma unroll 2
    for (int j = 0; j < GROUP_; ++j) {
        const int p = j & 1;

        v2 xjv[2];
        {
            float4 t = *(const float4*)&s_xj[p][d0];
            xjv[0] = (v2){t.x, t.y}; xjv[1] = (v2){t.z, t.w};
        }

        // sim = dot(xi,Wi) + dot(xj,Wj): packed FMAs, one 32-lane reduce.
        v2 sv = (v2){0.0f, 0.0f};
        sv = __builtin_elementwise_fma(xi[0],  Wi[0], sv);
        sv = __builtin_elementwise_fma(xi[1],  Wi[1], sv);
        sv = __builtin_elementwise_fma(xjv[0], Wj[0], sv);
        sv = __builtin_elementwise_fma(xjv[1], Wj[1], sv);
        const float sim = row32_sum(sv.x + sv.y);

        const v2 simv = (v2){sim, sim};
        const v2 cav  = (v2){ca, ca};
        const v2 onev = (v2){1.0f, 1.0f};
        const v2 leak = (v2){0.01f, 0.01f};

#pragma unroll
        for (int k = 0; k < 2; ++k) {
            // u = ca * (xi + sim*xj) = -2*a1*log2e * T
            v2 T2 = __builtin_elementwise_fma(simv, xjv[k], xi[k]);
            v2 u  = cav * T2;
            v2 e1 = (v2){__builtin_amdgcn_exp2f(u.x), __builtin_amdgcn_exp2f(u.y)};
            v2 d1 = e1 + onev;
            v2 r1 = (v2){__builtin_amdgcn_rcpf(d1.x), __builtin_amdgcn_rcpf(d1.y)}; // inf-safe
            v2 tnS = __builtin_elementwise_fma(G1S[k], r1, B1S[k]);  // S*(g1*tanh+b1)
            v2 alt = tnS * leak;
            v2 FvS = selMin ? __builtin_elementwise_min(tnS, alt)
                            : __builtin_elementwise_max(tnS, alt);
            za[k] += FvS;                                            // za = S * xa
            v2 e2 = (v2){__builtin_amdgcn_exp2f(za[k].x), __builtin_amdgcn_exp2f(za[k].y)};
            v2 d2 = e2 + onev;
            v2 r2 = (v2){__builtin_amdgcn_rcpf(d2.x), __builtin_amdgcn_rcpf(d2.y)};
            xi[k] = __builtin_elementwise_fma(G2[k], r2, xi[k] + B2[k]); // xi += g2*tanh+b2
        }

        // Next step's broadcaster writes the OTHER buffer; the single
        // barrier orders both visibility and WAR reuse.
        if (j + 1 < GROUP_ && row == j + 1) {
            float4 o = {xi[0].x, xi[0].y, xi[1].x, xi[1].y};
            *(float4*)&s_xj[p ^ 1][d0] = o;
        }
        __syncthreads();
    }

    // Recover xa = za / S
    const float invS = 1.0f / S;
    const v2 invSv = (v2){invS, invS};
    v2 xa[2];
    xa[0] = za[0] * invSv;
    xa[1] = za[1] * invSv;

    const bool valid = (g * GROUP_) < ctxlens[b];
    if (!valid) {
        xi[0] = (v2){0, 0}; xi[1] = (v2){0, 0};
        xa[0] = (v2){0, 0}; xa[1] = (v2){0, 0};
    }

    // Scatter back through the permutation (bijective -> every out elem written)
    float* o1 = out + ((size_t)(b * L_ + tok)) * D_ + d0;
    float* o2 = o1 + (size_t)B_ * L_ * D_;
    float4 s1 = {xi[0].x, xi[0].y, xi[1].x, xi[1].y};
    float4 s2 = {xa[0].x, xa[0].y, xa[1].x, xa[1].y};
    *(float4*)o1 = s1;
    *(float4*)o2 = s2;
}

extern "C" void kernel_launch(void* const* d_in, const int* in_sizes, int n_in,
                              void* d_out, int out_size, void* d_ws, size_t ws_size,
                              hipStream_t stream) {
    const float* x  = (const float*)d_in[0];
    const int*   gt = (const int*)d_in[1];
    const int*   cl = (const int*)d_in[2];
    const float* W  = (const float*)d_in[3];
    const float* na = (const float*)d_in[4];
    const float* ng = (const float*)d_in[5];
    const float* nb = (const float*)d_in[6];
    float* out = (float*)d_out;

    ncn_kernel<<<B_ * NG_, 512, 0, stream>>>(x, gt, cl, W, na, ng, nb, out);
}